// Round 14
// baseline (254.695 us; speedup 1.0000x reference)
//
#include <hip/hip_runtime.h>

// ConvAttention forward, MI355X. fp32 I/O, bf16 intermediates, MFMA GEMMs.
// R31 = R30 + two exact-math chain cuts in attention's dot phase:
//   (a) dot8 -> dot8v with EXPLICIT float4 LDS q-reads: 64 ds_read_b32 ->
//       16 ds_read_b128 per lane (~370 -> ~190 cyc DS-pipe per wave), both
//       patch and cls branches. Bitwise-identical math.
//   (b) patch softmax: expf(acc*SCALE) -> exp2f(acc*SCALE2) with
//       SCALE2 = SCALE*log2(e) — v_exp_f32 IS 2^x, so this drops the
//       compiler's internal xlog2e step. <=1 ulp drift (tol 0.0039).
// R30 (WIN, 253.8us): patch softmax fixed shift mx=0 (exact; pad key
//   contributes exp(0)=1 to Z). Removed the 5-shfl half_max chain.
// R29 (=R27, pinned): 256.4us reproduced (256.4/256.9/257.8 x3).
// R27: XCD-chunk swizzle of patch blocks (pbid'=(pbid&7)*192+pbid>>3):
//   attn FETCH 33.3->16.6MB (L2-thrash fixed; each XCD walks 6 panels).
// R24 (WIN): attention merged into ONE dispatch of 1024-thr blocks;
//   bid<48 = R17 16-wave cls block; bid>=48 = 16 independent patch waves.
// R19: global_load_lds GEMM staging (264.2 vs 274.5 baseline).
//   prologue = LN1 || cvt_weights(fp32->bf16) || zero(d_out)
//   qkv GEMM (128x128) -> attn_win (cls||patch) -> proj GEMM (+res)
//   -> midk (LN2 || zero tokf) -> pool GEMM (gather, split-K=4, atomic)
//   -> ln3 -> fc1 -> fc2.
// Negative results worth keeping (measured):
//   - BK=64 regressed (-18us)
//   - R20 dbuf+syncthreads: +21us; R25 dbuf+counted-vmcnt: +3us (GEMM
//     inner-loop pipelining CLOSED)
//   - R26 qkv TN64 + split-K6: +5.5us (GEMM launch config CLOSED)
//   - R18: cls as 48 SINGLE-WAVE blocks: 103us tail (PV serialization)
//   - R21: 4-wave repack of attn_patch: neutral; R23: LDS-staged K/V:
//     slightly negative; R28: per-wave ILP x2: +4.6us (attn packing CLOSED)
// ws (u16 units): h1 [0, 3151872) ; qkvb [3151872, 12607488) ;
//   wb [12607488, 15704064)  (bf16 weights: qkv|proj|pool|fc1|fc2)
//   att = q-cols of qkvb (lda 1152). After proj, qkvb region reused:
//   tokf (fp32) at qkvb+0 ; h3 at qkvb+1572864 ; mlp1 at qkvb+2362368.
// NOTE: tokf zeroing rides midk, stream-ordered AFTER proj (qkvb alias).

typedef unsigned short u16;
typedef unsigned int u32;
typedef short s16x8 __attribute__((ext_vector_type(8)));
typedef float f32x4 __attribute__((ext_vector_type(4)));

__device__ __forceinline__ float b2f(u16 u) {
    return __uint_as_float(((u32)u) << 16);
}
__device__ __forceinline__ u16 f2b(float f) {
    u32 u = __float_as_uint(f);
    return (u16)((u + 0x7FFFu + ((u >> 16) & 1u)) >> 16);  // RTNE
}
__device__ __forceinline__ void gload16(const void* g, void* l) {
    __builtin_amdgcn_global_load_lds(
        (const __attribute__((address_space(1))) void*)g,
        (__attribute__((address_space(3))) void*)l, 16, 0, 0);
}
__device__ __forceinline__ float wave_sum(float v) {
#pragma unroll
    for (int o = 32; o > 0; o >>= 1) v += __shfl_xor(v, o, 64);
    return v;
}
__device__ __forceinline__ float wave_max(float v) {
#pragma unroll
    for (int o = 32; o > 0; o >>= 1) v = fmaxf(v, __shfl_xor(v, o, 64));
    return v;
}
__device__ __forceinline__ float half_sum(float v) {
#pragma unroll
    for (int o = 16; o > 0; o >>= 1) v += __shfl_xor(v, o, 64);
    return v;
}
// R31: q operands preloaded as float4 pairs (16 ds_read_b128 vs 64 b32).
__device__ __forceinline__ float dot8v(float4 qa, float4 qb, uint4 u) {
    return qa.x * b2f((u16)(u.x)) + qa.y * b2f((u16)(u.x >> 16)) +
           qa.z * b2f((u16)(u.y)) + qa.w * b2f((u16)(u.y >> 16)) +
           qb.x * b2f((u16)(u.z)) + qb.y * b2f((u16)(u.z >> 16)) +
           qb.z * b2f((u16)(u.w)) + qb.w * b2f((u16)(u.w >> 16));
}

#define CCH 384
#define SCALE 0.40824829046386302f   // H^-0.5 = 6^-0.5
#define SCALE2 0.5889777846f         // SCALE * log2(e)  (R31: exp2 fold)
#define NEG_BIG (-1e30f)

// weight segment offsets in wb (u16 units)
#define W_QKV 0
#define W_PROJ 442368
#define W_POOL 589824
#define W_FC1 1916928
#define W_FC2 2506752
#define W_TOTAL 3096576

// ---------------- LN row helpers (per-wave, no block barriers) ---------------
__device__ __forceinline__ void ln_from_f32(const float* in, const float* w,
                                            const float* bb, u16* out,
                                            int lane) {
    float v[6];
    float s = 0.f, ss = 0.f;
#pragma unroll
    for (int i = 0; i < 6; i++) {
        v[i] = in[lane + 64 * i];
        s += v[i];
        ss += v[i] * v[i];
    }
    s = wave_sum(s);
    ss = wave_sum(ss);
    float mu = s * (1.f / 384.f);
    float var = ss * (1.f / 384.f) - mu * mu;
    float inv = rsqrtf(var + 1e-5f);
#pragma unroll
    for (int i = 0; i < 6; i++) {
        int c = lane + 64 * i;
        out[c] = f2b((v[i] - mu) * inv * w[c] + bb[c]);
    }
}
__device__ __forceinline__ void ln_from_b16(const u16* in, const float* w,
                                            const float* bb, u16* out,
                                            int lane) {
    float v[6];
    float s = 0.f, ss = 0.f;
#pragma unroll
    for (int i = 0; i < 6; i++) {
        v[i] = b2f(in[lane + 64 * i]);
        s += v[i];
        ss += v[i] * v[i];
    }
    s = wave_sum(s);
    ss = wave_sum(ss);
    float mu = s * (1.f / 384.f);
    float var = ss * (1.f / 384.f) - mu * mu;
    float inv = rsqrtf(var + 1e-5f);
#pragma unroll
    for (int i = 0; i < 6; i++) {
        int c = lane + 64 * i;
        out[c] = f2b((v[i] - mu) * inv * w[c] + bb[c]);
    }
}

// ---------------- prologue: LN1 || cvt_weights || zero(d_out) ----------------
#define PRO_LN 2052
#define PRO_CVT 1512
#define PRO_ZERO 771
__global__ __launch_bounds__(256) void prologue(
    const float* __restrict__ x, const float* __restrict__ n1w,
    const float* __restrict__ n1b, u16* __restrict__ h1,
    const float* __restrict__ qkv_w, const float* __restrict__ proj_w,
    const float* __restrict__ pool_w, const float* __restrict__ fc1_w,
    const float* __restrict__ fc2_w, u16* __restrict__ wb,
    float* __restrict__ dout) {
    int bid = blockIdx.x, tid = threadIdx.x;
    if (bid < PRO_LN) {
        int wv = tid >> 6, lane = tid & 63;
        int row = bid * 4 + wv;  // < 8208
        int t = row % 1026, b = row / 1026;
        u16* out = h1 + (size_t)row * CCH;
        if (t == 1025) {
#pragma unroll
            for (int i = 0; i < 6; i++) out[lane + 64 * i] = 0;
            return;
        }
        ln_from_f32(x + ((size_t)b * 1025 + t) * CCH, n1w, n1b, out, lane);
    } else if (bid < PRO_LN + PRO_CVT) {
        size_t off = ((size_t)(bid - PRO_LN) * 256 + tid) * 8;
        if (off >= W_TOTAL) return;
        const float* src;
        size_t base;
        if (off < W_PROJ)       { src = qkv_w;  base = W_QKV; }
        else if (off < W_POOL)  { src = proj_w; base = W_PROJ; }
        else if (off < W_FC1)   { src = pool_w; base = W_POOL; }
        else if (off < W_FC2)   { src = fc1_w;  base = W_FC1; }
        else                    { src = fc2_w;  base = W_FC2; }
        size_t rel = off - base;
        float4 a = *(const float4*)(src + rel);
        float4 b = *(const float4*)(src + rel + 4);
        uint4 o;
        o.x = (u32)f2b(a.x) | ((u32)f2b(a.y) << 16);
        o.y = (u32)f2b(a.z) | ((u32)f2b(a.w) << 16);
        o.z = (u32)f2b(b.x) | ((u32)f2b(b.y) << 16);
        o.w = (u32)f2b(b.z) | ((u32)f2b(b.w) << 16);
        *(uint4*)(wb + off) = o;
    } else {
        size_t idx = ((size_t)(bid - PRO_LN - PRO_CVT) * 256 + tid) * 4;
        *(float4*)(dout + idx) = make_float4(0.f, 0.f, 0.f, 0.f);
    }
}

// ---------------- midk: LN2 (in-place) || zero(tokf) -------------------------
#define MID_LN 2050
#define MID_ZERO 768
__global__ __launch_bounds__(256) void midk(u16* __restrict__ h,
                                            const float* __restrict__ n2w,
                                            const float* __restrict__ n2b,
                                            float* __restrict__ tokf) {
    int bid = blockIdx.x, tid = threadIdx.x;
    if (bid < MID_LN) {
        int wv = tid >> 6, lane = tid & 63;
        int row = bid * 4 + wv;  // < 8200
        int b = row / 1025, t = row % 1025;
        u16* p = h + ((size_t)b * 1026 + t) * CCH;
        ln_from_b16(p, n2w, n2b, p, lane);
    } else {
        size_t idx = ((size_t)(bid - MID_LN) * 256 + tid) * 4;
        *(float4*)(tokf + idx) = make_float4(0.f, 0.f, 0.f, 0.f);
    }
}

// h3 = LN3(concat(h2[:,0] (bf16), tokf (fp32, pool bias included)))
// 4 independent waves per block (no barrier), row = bid*4 + wave.
__global__ __launch_bounds__(256) void ln3_concat(const u16* __restrict__ h2,
                                                  const float* __restrict__ tokf,
                                                  const float* __restrict__ w,
                                                  const float* __restrict__ bb,
                                                  u16* __restrict__ h3) {
    int tid = threadIdx.x;
    int wv = tid >> 6, lane = tid & 63;
    int row = blockIdx.x * 4 + wv;  // < 2056 = b*257 + t
    int b = row / 257, t = row % 257;
    u16* out = h3 + (size_t)row * CCH;
    if (t == 0) {
        ln_from_b16(h2 + (size_t)b * 1026 * CCH, w, bb, out, lane);
    } else {
        ln_from_f32(tokf + ((size_t)b * 256 + (t - 1)) * CCH, w, bb, out, lane);
    }
}

// ---------------- MFMA GEMM (bf16 A, bf16 pre-converted weights) -------------
// Y[M,N] = act(A[M,K]bf16 @ Wb[N,K]bf16^T + bias) (+Res bf16)
// Tile 128xTN (TN in {64,128}), 4 waves, BK=32.  (R19-proven, do not touch.)
// Staging: global_load_lds width=16, LDS linear pitch 32 u16. XOR swizzle
// seg^=row&3 applied on the GLOBAL source address (LDS dest stays linear,
// required by global_load_lds lane ordering) and matched on the fragment
// ds_read_b128.
// GATHER: A row m gathers 3x3 window of h2 (pool). SPLITK: blockIdx.z splits K;
// ATOMIC: fp32 atomicAdd into Yv (zero-initialized), bias added by kp==0.
template <int TN, bool GATHER, int SPLITK, bool BIAS, bool GELU_ACT, bool RES,
          bool ATOMIC>
__global__ __launch_bounds__(256) void gemm_mf(const u16* __restrict__ A,
                                               int lda,
                                               const u16* __restrict__ Bwb,
                                               const float* __restrict__ bias,
                                               const u16* __restrict__ Res,
                                               void* __restrict__ Yv, int M,
                                               int N, int K) {
    __shared__ u16 Asl[128 * 32];
    __shared__ u16 Bsl[TN * 32];
    const int tid = threadIdx.x;
    const int wave = tid >> 6, lane = tid & 63;
    const int quad = lane >> 4, l15 = lane & 15;
    const int wvu = __builtin_amdgcn_readfirstlane(wave);  // SGPR wave id
    const int m0 = blockIdx.y * 128, n0 = blockIdx.x * TN;
    const int kp = (SPLITK > 1) ? blockIdx.z : 0;
    const int KS = K / SPLITK;
    const int kbase = kp * KS;
    // stage source indices: thread covers (row = L*64 + tid>>2, seg = tid&3),
    // fetches swizzled source segment sseg = seg ^ (row&3) into linear LDS.
    const int srow = tid >> 2;
    const int sseg = (tid & 3) ^ (srow & 3);

    f32x4 acc[2][TN / 16];
#pragma unroll
    for (int i = 0; i < 2; i++)
#pragma unroll
        for (int j = 0; j < TN / 16; j++) acc[i][j] = (f32x4){0.f, 0.f, 0.f, 0.f};

    for (int kt = 0; kt < KS; kt += 32) {
        const int kk = kbase + kt;
        const int kf = kk + sseg * 8;
#pragma unroll
        for (int L = 0; L < 2; L++) {
            int row = L * 64 + srow;
            const u16* src;
            if (GATHER) {
                int m = m0 + row;
                int b = m >> 8, w = m & 255;
                int j = kf / 384, rem = kf - j * 384;
                int pr = 2 * (w >> 4) + j / 3 - 1;
                int pc = 2 * (w & 15) + j % 3 - 1;
                int tok = (pr >= 0 && pr < 32 && pc >= 0 && pc < 32)
                              ? (32 * pr + pc + 1)
                              : 1024;
                src = A + ((size_t)b * 1026 + tok) * 384 + rem;
            } else {
                int m = m0 + row;
                if (m >= M) m = M - 1;
                src = A + (size_t)m * lda + kf;
            }
            gload16(src, &Asl[(size_t)(L * 256 + wvu * 64) * 8]);
        }
#pragma unroll
        for (int L = 0; L < TN / 64; L++) {
            int row = L * 64 + srow;
            gload16(Bwb + (size_t)(n0 + row) * K + kf,
                    &Bsl[(size_t)(L * 256 + wvu * 64) * 8]);
        }
        __syncthreads();  // drains vmcnt(0) before barrier
        s16x8 afr[2], bfr[TN / 16];
        const int rslot = (quad ^ (l15 & 3)) * 8;  // inverse of source swizzle
#pragma unroll
        for (int ms = 0; ms < 2; ms++)
            afr[ms] =
                *(const s16x8*)(&Asl[(wave * 32 + ms * 16 + l15) * 32 + rslot]);
#pragma unroll
        for (int ns = 0; ns < TN / 16; ns++)
            bfr[ns] = *(const s16x8*)(&Bsl[(ns * 16 + l15) * 32 + rslot]);
#pragma unroll
        for (int ms = 0; ms < 2; ms++)
#pragma unroll
            for (int ns = 0; ns < TN / 16; ns++)
                acc[ms][ns] = __builtin_amdgcn_mfma_f32_16x16x32_bf16(
                    afr[ms], bfr[ns], acc[ms][ns], 0, 0, 0);
        __syncthreads();
    }
#pragma unroll
    for (int ms = 0; ms < 2; ms++) {
#pragma unroll
        for (int ns = 0; ns < TN / 16; ns++) {
            int n = n0 + ns * 16 + l15;
#pragma unroll
            for (int i = 0; i < 4; i++) {
                int m = m0 + wave * 32 + ms * 16 + quad * 4 + i;
                if (m >= M) continue;
                float v = acc[ms][ns][i];
                if (BIAS && (SPLITK == 1 || kp == 0)) v += bias[n];
                if (RES) v += b2f(Res[(size_t)m * N + n]);
                if (GELU_ACT) v = 0.5f * v * (1.f + erff(v * 0.70710678118f));
                if (ATOMIC)
                    atomicAdd((float*)Yv + (size_t)m * N + n, v);
                else
                    ((u16*)Yv)[(size_t)m * N + n] = f2b(v);
            }
        }
    }
}

// ---------------- attention: cls (48 leading blocks) + patch, 1024-thr -------
// bid < 48: R17-proven CLS block (R31: float4 q-reads in dot phase).
// bid >= 48: 16 INDEPENDENT patch waves. R27: XCD-chunk swizzled
//   (pbid' = (pbid&7)*192 + pbid>>3, bijective over 1536) so each XCD walks
//   6 (b,h) panels sequentially (measured: FETCH 33.3MB -> 16.6MB).
// R30: patch softmax fixed shift mx=0 (exact; pad key adds exp(0)=1 to Z).
// R31: dot phase reads q as float4 pairs; patch exp via exp2f(acc*SCALE2).
__global__ __launch_bounds__(1024) void attn_win(u16* __restrict__ qkv) {
    int bid = blockIdx.x;
    int tid = threadIdx.x;
    if (bid < 48) {
        int h = bid % 6, b = bid / 6;
        u16* base = qkv + (size_t)b * 1026 * 1152 + h * 64;
        int lane = tid & 63, wv = tid >> 6;  // wv 0..15
        __shared__ float sc[1026];
        __shared__ float qsh[64];
        __shared__ float redmax[16], redsum[16];
        __shared__ float pv[16][64];
        if (tid < 64) qsh[tid] = b2f(base[tid]);
        __syncthreads();
        for (int key = tid; key < 1026; key += 1024) {
            const u16* krow = base + (size_t)key * 1152 + 384;
            float acc = 0.f;
#pragma unroll
            for (int d0 = 0; d0 < 64; d0 += 8) {
                float4 qa = *(const float4*)(qsh + d0);
                float4 qb = *(const float4*)(qsh + d0 + 4);
                acc += dot8v(qa, qb, *(const uint4*)(krow + d0));
            }
            sc[key] = acc * SCALE;
        }
        __syncthreads();
        float lm = NEG_BIG;
        for (int key = tid; key < 1026; key += 1024) lm = fmaxf(lm, sc[key]);
        lm = wave_max(lm);
        if (lane == 0) redmax[wv] = lm;
        __syncthreads();
        float mx = NEG_BIG;
#pragma unroll
        for (int i = 0; i < 16; i++) mx = fmaxf(mx, redmax[i]);
        float lsum = 0.f;
        for (int key = tid; key < 1026; key += 1024) {
            float e = expf(sc[key] - mx);
            sc[key] = e;
            lsum += e;
        }
        lsum = wave_sum(lsum);
        if (lane == 0) redsum[wv] = lsum;
        __syncthreads();
        float Z = 0.f;
#pragma unroll
        for (int i = 0; i < 16; i++) Z += redsum[i];
        float acc = 0.f;
#pragma unroll
        for (int t = 0; t < 65; t++) {
            int key = wv + 16 * t;
            bool ok = key < 1026;
            int kc = ok ? key : 1025;  // row 1025 = zero pad row
            float p = ok ? sc[kc] : 0.f;
            acc += p * b2f(base[(size_t)kc * 1152 + 768 + lane]);
        }
        pv[wv][lane] = acc;
        __syncthreads();
        if (tid < 64) {
            float s = 0.f;
#pragma unroll
            for (int w2 = 0; w2 < 16; w2++) s += pv[w2][tid];
            base[tid] = f2b(s / Z);
            base[(size_t)1025 * 1152 + tid] = 0;  // att pad row (q-cols)
        }
        return;
    }
    // ---- patch branch: 16 independent waves, no barriers ----
    __shared__ float qshp[16][2][64];
    int pbid = bid - 48;
    pbid = (pbid & 7) * 192 + (pbid >> 3);  // R27 XCD-chunk swizzle (bijective)
    int wv = tid >> 6, lane = tid & 63;
    int pair = pbid * 16 + wv;  // < 24576
    int idx = pair & 511;
    int hb = pair >> 9;
    int h = hb % 6, b = hb / 6;
    int hl = lane >> 5, l5 = lane & 31;
    int p0 = idx * 2;
    int p = p0 | hl;  // p0 even
    int r = p >> 5, c = p & 31;
    int rlo, rhi, clo, chi;
    if (r & 1) { rlo = (r - 2 < 0) ? 0 : r - 2; rhi = (r + 2 > 31) ? 31 : r + 2; }
    else       { rlo = (r - 1 < 0) ? 0 : r - 1; rhi = (r + 1 > 31) ? 31 : r + 1; }
    if (c & 1) { clo = (c - 2 < 0) ? 0 : c - 2; chi = (c + 2 > 31) ? 31 : c + 2; }
    else       { clo = (c - 1 < 0) ? 0 : c - 1; chi = (c + 1 > 31) ? 31 : c + 1; }
    int nr = rhi - rlo + 1, nc = chi - clo + 1;
    int nk = nr * nc + 1;  // + CLS at slot 0 (per half); nk in [5,26]
    int tok = 0;           // slot 0 = CLS (token 0); also lanes >= nk
    if (l5 >= 1 && l5 < nk) {
        int jj = l5 - 1;
        tok = 1 + ((rlo + jj / nc) << 5) + (clo + jj % nc);
    }
    u16* base = qkv + (size_t)b * 1026 * 1152 + h * 64;
    qshp[wv][0][lane] = b2f(base[(size_t)(1 + p0) * 1152 + lane]);
    qshp[wv][1][lane] = b2f(base[(size_t)(2 + p0) * 1152 + lane]);
    // no barrier: same-wave LDS write->read, DS pipeline orders it.
    float pe = 0.f;
    if (l5 < nk) {
        const u16* krow = base + (size_t)tok * 1152 + 384;
        const float* qv = qshp[wv][hl];
        float acc = 0.f;
#pragma unroll
        for (int d0 = 0; d0 < 64; d0 += 8) {
            float4 qa = *(const float4*)(qv + d0);
            float4 qb = *(const float4*)(qv + d0 + 4);
            acc += dot8v(qa, qb, *(const uint4*)(krow + d0));
        }
        // R30/R31: fixed shift mx=0 (exact), exp2 fold (v_exp_f32 is 2^x).
        pe = exp2f(acc * SCALE2);
    }
    float Z = half_sum(pe) + 1.f;  // pad key contributes exp(0)=1
    // PV: each half handles its own query; lane covers dims 2*l5, 2*l5+1.
    float o0 = 0.f, o1 = 0.f;
#pragma unroll
    for (int j = 0; j < 26; j++) {
        int t = __shfl(tok, (hl << 5) | j, 64);
        float wj = __shfl(pe, (hl << 5) | j, 64);
        u32 vv = *(const u32*)(base + (size_t)t * 1152 + 768 + 2 * l5);
        o0 += wj * b2f((u16)vv);
        o1 += wj * b2f((u16)(vv >> 16));
    }
    float zi = 1.f / Z;
    u32 packed = (u32)f2b(o0 * zi) | ((u32)f2b(o1 * zi) << 16);
    *(u32*)(base + (size_t)(1 + p) * 1152 + 2 * l5) = packed;
}

extern "C" void kernel_launch(void* const* d_in, const int* in_sizes, int n_in,
                              void* d_out, int out_size, void* d_ws,
                              size_t ws_size, hipStream_t stream) {
    const float* x      = (const float*)d_in[0];
    const float* n1w    = (const float*)d_in[1];
    const float* n1b    = (const float*)d_in[2];
    const float* qkv_w  = (const float*)d_in[3];
    const float* proj_w = (const float*)d_in[4];
    const float* proj_b = (const float*)d_in[5];
    const float* n2w    = (const float*)d_in[6];
    const float* n2b    = (const float*)d_in[7];
    const float* pool_w = (const float*)d_in[8];
    const float* pool_b = (const float*)d_in[9];
    const float* n3w    = (const float*)d_in[10];
    const float* n3b    = (const float*)d_in[11];
    const float* fc1_w  = (const float*)d_in[12];
    const float* fc1_b  = (const float*)d_in[13];
    const float* fc2_w  = (const float*)d_in[14];
    const float* fc2_b  = (const float*)d_in[15];

    u16* ws = (u16*)d_ws;
    u16* h1    = ws;                      // 8208*384
    u16* qkvb  = ws + 3151872;            // 8208*1152
    u16* wb    = ws + 12607488;           // 3,096,576 bf16 weights
    float* tokf = (float*)qkvb;           // 2048*384 fp32 (reuse after proj)
    u16* h3    = qkvb + 1572864;          // 2056*384
    u16* mlp1  = qkvb + 2362368;          // 2056*1536

    // 0. prologue: LN1 || weight cvt || zero d_out (split-K accumulator)
    prologue<<<PRO_LN + PRO_CVT + PRO_ZERO, 256, 0, stream>>>(
        x, n1w, n1b, h1, qkv_w, proj_w, pool_w, fc1_w, fc2_w, wb,
        (float*)d_out);
    // 1. qkv = h1 @ qkv_w^T  (8208 x 1152 x 384), 128x128 tile
    gemm_mf<128, false, 1, false, false, false, false>
        <<<dim3(1152 / 128, 65), 256, 0, stream>>>(h1, 384, wb + W_QKV,
                                                   nullptr, nullptr, qkvb,
                                                   8208, 1152, 384);
    // 2. attention (cls leads || patch, XCD-swizzled) -> q-cols of qkvb
    attn_win<<<48 + 24576 / 16, 1024, 0, stream>>>(qkvb);
    // 3. h1 = h1 + att @ proj_w^T + proj_b  (A = qkvb q-cols, lda=1152)
    gemm_mf<64, false, 1, true, false, true, false>
        <<<dim3(384 / 64, 65), 256, 0, stream>>>(qkvb, 1152, wb + W_PROJ,
                                                 proj_b, h1, h1, 8208, 384,
                                                 384);
    // 4. midk: LN2 in-place || zero tokf (aliases qkvb — dead after proj)
    midk<<<MID_LN + MID_ZERO, 256, 0, stream>>>(h1, n2w, n2b, tokf);
    // 5. tokf += gather(h1) @ pool_w^T (+ pool_b on kp==0)  split-K=4
    gemm_mf<64, true, 4, true, false, false, true>
        <<<dim3(384 / 64, 16, 4), 256, 0, stream>>>(h1, 384, wb + W_POOL,
                                                    pool_b, nullptr, tokf,
                                                    2048, 384, 3456);
    // 6. h3 = LN3(concat(h1[:,0], tokf))  (514 blocks x 4 waves)
    ln3_concat<<<8 * 257 / 4, 256, 0, stream>>>(h1, tokf, n3w, n3b, h3);
    // 7. mlp1 = gelu(h3 @ fc1_w^T + fc1_b)  (2056 x 1536 x 384)
    gemm_mf<64, false, 1, true, true, false, false>
        <<<dim3(1536 / 64, 17), 256, 0, stream>>>(h3, 384, wb + W_FC1, fc1_b,
                                                  nullptr, mlp1, 2056, 1536,
                                                  384);
    // 8. d_out += mlp1 @ fc2_w^T (+ fc2_b on kp==0)  split-K=4, fp32 out
    gemm_mf<64, false, 4, true, false, false, true>
        <<<dim3(384 / 64, 17, 4), 256, 0, stream>>>(mlp1, 1536, wb + W_FC2,
                                                    fc2_b, nullptr, d_out,
                                                    2056, 384, 1536);
}

// Round 15
// 251.114 us; speedup vs baseline: 1.0143x; 1.0143x over previous
//
#include <hip/hip_runtime.h>

// ConvAttention forward, MI355X. fp32 I/O, bf16 intermediates, MFMA GEMMs.
// R32 = R31 + patch-PV shuffle pair -> LDS broadcast: the (tok, pe) values
//   for trip j are UNIFORM within each 32-lane half, so the 2 ds_bpermute
//   per trip (52 DS ops/wave) become 1 ds_write_b64 + 26 ds_read_b64 at
//   half-uniform addresses (2 addrs/wave = 2-way, free; broadcast within
//   half). Bitwise-identical values, same FMA order. LDS +8KB (24.4KB).
// R31 (254.7us, =R30 within noise): float4 q-reads + exp2 fold (neutral).
// R30 (WIN, 253.8us): patch softmax fixed shift mx=0 (exact; pad key
//   contributes exp(0)=1 to Z). Removed the 5-shfl half_max chain.
// R29 (=R27, pinned): 256.4us reproduced (256.4/256.9/257.8 x3).
// R27: XCD-chunk swizzle of patch blocks (pbid'=(pbid&7)*192+pbid>>3):
//   attn FETCH 33.3->16.6MB (L2-thrash fixed; each XCD walks 6 panels).
// R24 (WIN): attention merged into ONE dispatch of 1024-thr blocks;
//   bid<48 = R17 16-wave cls block; bid>=48 = 16 independent patch waves.
// R19: global_load_lds GEMM staging (264.2 vs 274.5 baseline).
//   prologue = LN1 || cvt_weights(fp32->bf16) || zero(d_out)
//   qkv GEMM (128x128) -> attn_win (cls||patch) -> proj GEMM (+res)
//   -> midk (LN2 || zero tokf) -> pool GEMM (gather, split-K=4, atomic)
//   -> ln3 -> fc1 -> fc2.
// Negative results worth keeping (measured):
//   - BK=64 regressed (-18us)
//   - R20 dbuf+syncthreads: +21us; R25 dbuf+counted-vmcnt: +3us (GEMM
//     inner-loop pipelining CLOSED)
//   - R26 qkv TN64 + split-K6: +5.5us (GEMM launch config CLOSED)
//   - R18: cls as 48 SINGLE-WAVE blocks: 103us tail (PV serialization)
//   - R21: 4-wave repack of attn_patch: neutral; R23: LDS-staged K/V:
//     slightly negative; R28: per-wave ILP x2: +4.6us (attn packing CLOSED)
// ws (u16 units): h1 [0, 3151872) ; qkvb [3151872, 12607488) ;
//   wb [12607488, 15704064)  (bf16 weights: qkv|proj|pool|fc1|fc2)
//   att = q-cols of qkvb (lda 1152). After proj, qkvb region reused:
//   tokf (fp32) at qkvb+0 ; h3 at qkvb+1572864 ; mlp1 at qkvb+2362368.
// NOTE: tokf zeroing rides midk, stream-ordered AFTER proj (qkvb alias).

typedef unsigned short u16;
typedef unsigned int u32;
typedef short s16x8 __attribute__((ext_vector_type(8)));
typedef float f32x4 __attribute__((ext_vector_type(4)));

__device__ __forceinline__ float b2f(u16 u) {
    return __uint_as_float(((u32)u) << 16);
}
__device__ __forceinline__ u16 f2b(float f) {
    u32 u = __float_as_uint(f);
    return (u16)((u + 0x7FFFu + ((u >> 16) & 1u)) >> 16);  // RTNE
}
__device__ __forceinline__ void gload16(const void* g, void* l) {
    __builtin_amdgcn_global_load_lds(
        (const __attribute__((address_space(1))) void*)g,
        (__attribute__((address_space(3))) void*)l, 16, 0, 0);
}
__device__ __forceinline__ float wave_sum(float v) {
#pragma unroll
    for (int o = 32; o > 0; o >>= 1) v += __shfl_xor(v, o, 64);
    return v;
}
__device__ __forceinline__ float wave_max(float v) {
#pragma unroll
    for (int o = 32; o > 0; o >>= 1) v = fmaxf(v, __shfl_xor(v, o, 64));
    return v;
}
__device__ __forceinline__ float half_sum(float v) {
#pragma unroll
    for (int o = 16; o > 0; o >>= 1) v += __shfl_xor(v, o, 64);
    return v;
}
// R31: q operands preloaded as float4 pairs (16 ds_read_b128 vs 64 b32).
__device__ __forceinline__ float dot8v(float4 qa, float4 qb, uint4 u) {
    return qa.x * b2f((u16)(u.x)) + qa.y * b2f((u16)(u.x >> 16)) +
           qa.z * b2f((u16)(u.y)) + qa.w * b2f((u16)(u.y >> 16)) +
           qb.x * b2f((u16)(u.z)) + qb.y * b2f((u16)(u.z >> 16)) +
           qb.z * b2f((u16)(u.w)) + qb.w * b2f((u16)(u.w >> 16));
}

#define CCH 384
#define SCALE 0.40824829046386302f   // H^-0.5 = 6^-0.5
#define SCALE2 0.5889777846f         // SCALE * log2(e)  (R31: exp2 fold)
#define NEG_BIG (-1e30f)

// weight segment offsets in wb (u16 units)
#define W_QKV 0
#define W_PROJ 442368
#define W_POOL 589824
#define W_FC1 1916928
#define W_FC2 2506752
#define W_TOTAL 3096576

// ---------------- LN row helpers (per-wave, no block barriers) ---------------
__device__ __forceinline__ void ln_from_f32(const float* in, const float* w,
                                            const float* bb, u16* out,
                                            int lane) {
    float v[6];
    float s = 0.f, ss = 0.f;
#pragma unroll
    for (int i = 0; i < 6; i++) {
        v[i] = in[lane + 64 * i];
        s += v[i];
        ss += v[i] * v[i];
    }
    s = wave_sum(s);
    ss = wave_sum(ss);
    float mu = s * (1.f / 384.f);
    float var = ss * (1.f / 384.f) - mu * mu;
    float inv = rsqrtf(var + 1e-5f);
#pragma unroll
    for (int i = 0; i < 6; i++) {
        int c = lane + 64 * i;
        out[c] = f2b((v[i] - mu) * inv * w[c] + bb[c]);
    }
}
__device__ __forceinline__ void ln_from_b16(const u16* in, const float* w,
                                            const float* bb, u16* out,
                                            int lane) {
    float v[6];
    float s = 0.f, ss = 0.f;
#pragma unroll
    for (int i = 0; i < 6; i++) {
        v[i] = b2f(in[lane + 64 * i]);
        s += v[i];
        ss += v[i] * v[i];
    }
    s = wave_sum(s);
    ss = wave_sum(ss);
    float mu = s * (1.f / 384.f);
    float var = ss * (1.f / 384.f) - mu * mu;
    float inv = rsqrtf(var + 1e-5f);
#pragma unroll
    for (int i = 0; i < 6; i++) {
        int c = lane + 64 * i;
        out[c] = f2b((v[i] - mu) * inv * w[c] + bb[c]);
    }
}

// ---------------- prologue: LN1 || cvt_weights || zero(d_out) ----------------
#define PRO_LN 2052
#define PRO_CVT 1512
#define PRO_ZERO 771
__global__ __launch_bounds__(256) void prologue(
    const float* __restrict__ x, const float* __restrict__ n1w,
    const float* __restrict__ n1b, u16* __restrict__ h1,
    const float* __restrict__ qkv_w, const float* __restrict__ proj_w,
    const float* __restrict__ pool_w, const float* __restrict__ fc1_w,
    const float* __restrict__ fc2_w, u16* __restrict__ wb,
    float* __restrict__ dout) {
    int bid = blockIdx.x, tid = threadIdx.x;
    if (bid < PRO_LN) {
        int wv = tid >> 6, lane = tid & 63;
        int row = bid * 4 + wv;  // < 8208
        int t = row % 1026, b = row / 1026;
        u16* out = h1 + (size_t)row * CCH;
        if (t == 1025) {
#pragma unroll
            for (int i = 0; i < 6; i++) out[lane + 64 * i] = 0;
            return;
        }
        ln_from_f32(x + ((size_t)b * 1025 + t) * CCH, n1w, n1b, out, lane);
    } else if (bid < PRO_LN + PRO_CVT) {
        size_t off = ((size_t)(bid - PRO_LN) * 256 + tid) * 8;
        if (off >= W_TOTAL) return;
        const float* src;
        size_t base;
        if (off < W_PROJ)       { src = qkv_w;  base = W_QKV; }
        else if (off < W_POOL)  { src = proj_w; base = W_PROJ; }
        else if (off < W_FC1)   { src = pool_w; base = W_POOL; }
        else if (off < W_FC2)   { src = fc1_w;  base = W_FC1; }
        else                    { src = fc2_w;  base = W_FC2; }
        size_t rel = off - base;
        float4 a = *(const float4*)(src + rel);
        float4 b = *(const float4*)(src + rel + 4);
        uint4 o;
        o.x = (u32)f2b(a.x) | ((u32)f2b(a.y) << 16);
        o.y = (u32)f2b(a.z) | ((u32)f2b(a.w) << 16);
        o.z = (u32)f2b(b.x) | ((u32)f2b(b.y) << 16);
        o.w = (u32)f2b(b.z) | ((u32)f2b(b.w) << 16);
        *(uint4*)(wb + off) = o;
    } else {
        size_t idx = ((size_t)(bid - PRO_LN - PRO_CVT) * 256 + tid) * 4;
        *(float4*)(dout + idx) = make_float4(0.f, 0.f, 0.f, 0.f);
    }
}

// ---------------- midk: LN2 (in-place) || zero(tokf) -------------------------
#define MID_LN 2050
#define MID_ZERO 768
__global__ __launch_bounds__(256) void midk(u16* __restrict__ h,
                                            const float* __restrict__ n2w,
                                            const float* __restrict__ n2b,
                                            float* __restrict__ tokf) {
    int bid = blockIdx.x, tid = threadIdx.x;
    if (bid < MID_LN) {
        int wv = tid >> 6, lane = tid & 63;
        int row = bid * 4 + wv;  // < 8200
        int b = row / 1025, t = row % 1025;
        u16* p = h + ((size_t)b * 1026 + t) * CCH;
        ln_from_b16(p, n2w, n2b, p, lane);
    } else {
        size_t idx = ((size_t)(bid - MID_LN) * 256 + tid) * 4;
        *(float4*)(tokf + idx) = make_float4(0.f, 0.f, 0.f, 0.f);
    }
}

// h3 = LN3(concat(h2[:,0] (bf16), tokf (fp32, pool bias included)))
// 4 independent waves per block (no barrier), row = bid*4 + wave.
__global__ __launch_bounds__(256) void ln3_concat(const u16* __restrict__ h2,
                                                  const float* __restrict__ tokf,
                                                  const float* __restrict__ w,
                                                  const float* __restrict__ bb,
                                                  u16* __restrict__ h3) {
    int tid = threadIdx.x;
    int wv = tid >> 6, lane = tid & 63;
    int row = blockIdx.x * 4 + wv;  // < 2056 = b*257 + t
    int b = row / 257, t = row % 257;
    u16* out = h3 + (size_t)row * CCH;
    if (t == 0) {
        ln_from_b16(h2 + (size_t)b * 1026 * CCH, w, bb, out, lane);
    } else {
        ln_from_f32(tokf + ((size_t)b * 256 + (t - 1)) * CCH, w, bb, out, lane);
    }
}

// ---------------- MFMA GEMM (bf16 A, bf16 pre-converted weights) -------------
// Y[M,N] = act(A[M,K]bf16 @ Wb[N,K]bf16^T + bias) (+Res bf16)
// Tile 128xTN (TN in {64,128}), 4 waves, BK=32.  (R19-proven, do not touch.)
// Staging: global_load_lds width=16, LDS linear pitch 32 u16. XOR swizzle
// seg^=row&3 applied on the GLOBAL source address (LDS dest stays linear,
// required by global_load_lds lane ordering) and matched on the fragment
// ds_read_b128.
// GATHER: A row m gathers 3x3 window of h2 (pool). SPLITK: blockIdx.z splits K;
// ATOMIC: fp32 atomicAdd into Yv (zero-initialized), bias added by kp==0.
template <int TN, bool GATHER, int SPLITK, bool BIAS, bool GELU_ACT, bool RES,
          bool ATOMIC>
__global__ __launch_bounds__(256) void gemm_mf(const u16* __restrict__ A,
                                               int lda,
                                               const u16* __restrict__ Bwb,
                                               const float* __restrict__ bias,
                                               const u16* __restrict__ Res,
                                               void* __restrict__ Yv, int M,
                                               int N, int K) {
    __shared__ u16 Asl[128 * 32];
    __shared__ u16 Bsl[TN * 32];
    const int tid = threadIdx.x;
    const int wave = tid >> 6, lane = tid & 63;
    const int quad = lane >> 4, l15 = lane & 15;
    const int wvu = __builtin_amdgcn_readfirstlane(wave);  // SGPR wave id
    const int m0 = blockIdx.y * 128, n0 = blockIdx.x * TN;
    const int kp = (SPLITK > 1) ? blockIdx.z : 0;
    const int KS = K / SPLITK;
    const int kbase = kp * KS;
    // stage source indices: thread covers (row = L*64 + tid>>2, seg = tid&3),
    // fetches swizzled source segment sseg = seg ^ (row&3) into linear LDS.
    const int srow = tid >> 2;
    const int sseg = (tid & 3) ^ (srow & 3);

    f32x4 acc[2][TN / 16];
#pragma unroll
    for (int i = 0; i < 2; i++)
#pragma unroll
        for (int j = 0; j < TN / 16; j++) acc[i][j] = (f32x4){0.f, 0.f, 0.f, 0.f};

    for (int kt = 0; kt < KS; kt += 32) {
        const int kk = kbase + kt;
        const int kf = kk + sseg * 8;
#pragma unroll
        for (int L = 0; L < 2; L++) {
            int row = L * 64 + srow;
            const u16* src;
            if (GATHER) {
                int m = m0 + row;
                int b = m >> 8, w = m & 255;
                int j = kf / 384, rem = kf - j * 384;
                int pr = 2 * (w >> 4) + j / 3 - 1;
                int pc = 2 * (w & 15) + j % 3 - 1;
                int tok = (pr >= 0 && pr < 32 && pc >= 0 && pc < 32)
                              ? (32 * pr + pc + 1)
                              : 1024;
                src = A + ((size_t)b * 1026 + tok) * 384 + rem;
            } else {
                int m = m0 + row;
                if (m >= M) m = M - 1;
                src = A + (size_t)m * lda + kf;
            }
            gload16(src, &Asl[(size_t)(L * 256 + wvu * 64) * 8]);
        }
#pragma unroll
        for (int L = 0; L < TN / 64; L++) {
            int row = L * 64 + srow;
            gload16(Bwb + (size_t)(n0 + row) * K + kf,
                    &Bsl[(size_t)(L * 256 + wvu * 64) * 8]);
        }
        __syncthreads();  // drains vmcnt(0) before barrier
        s16x8 afr[2], bfr[TN / 16];
        const int rslot = (quad ^ (l15 & 3)) * 8;  // inverse of source swizzle
#pragma unroll
        for (int ms = 0; ms < 2; ms++)
            afr[ms] =
                *(const s16x8*)(&Asl[(wave * 32 + ms * 16 + l15) * 32 + rslot]);
#pragma unroll
        for (int ns = 0; ns < TN / 16; ns++)
            bfr[ns] = *(const s16x8*)(&Bsl[(ns * 16 + l15) * 32 + rslot]);
#pragma unroll
        for (int ms = 0; ms < 2; ms++)
#pragma unroll
            for (int ns = 0; ns < TN / 16; ns++)
                acc[ms][ns] = __builtin_amdgcn_mfma_f32_16x16x32_bf16(
                    afr[ms], bfr[ns], acc[ms][ns], 0, 0, 0);
        __syncthreads();
    }
#pragma unroll
    for (int ms = 0; ms < 2; ms++) {
#pragma unroll
        for (int ns = 0; ns < TN / 16; ns++) {
            int n = n0 + ns * 16 + l15;
#pragma unroll
            for (int i = 0; i < 4; i++) {
                int m = m0 + wave * 32 + ms * 16 + quad * 4 + i;
                if (m >= M) continue;
                float v = acc[ms][ns][i];
                if (BIAS && (SPLITK == 1 || kp == 0)) v += bias[n];
                if (RES) v += b2f(Res[(size_t)m * N + n]);
                if (GELU_ACT) v = 0.5f * v * (1.f + erff(v * 0.70710678118f));
                if (ATOMIC)
                    atomicAdd((float*)Yv + (size_t)m * N + n, v);
                else
                    ((u16*)Yv)[(size_t)m * N + n] = f2b(v);
            }
        }
    }
}

// ---------------- attention: cls (48 leading blocks) + patch, 1024-thr -------
// bid < 48: R17-proven CLS block (R31: float4 q-reads in dot phase).
// bid >= 48: 16 INDEPENDENT patch waves. R27: XCD-chunk swizzled
//   (pbid' = (pbid&7)*192 + pbid>>3, bijective over 1536) so each XCD walks
//   6 (b,h) panels sequentially (measured: FETCH 33.3MB -> 16.6MB).
// R30: patch softmax fixed shift mx=0 (exact; pad key adds exp(0)=1 to Z).
// R31: dot phase reads q as float4 pairs; patch exp via exp2f(acc*SCALE2).
// R32: PV (tok,pe) via LDS broadcast (uint2 write once + uniform-addr
//   ds_read_b64 per trip) instead of 2 ds_bpermute per trip: 52 -> 27 DS
//   ops/wave. Bitwise-identical values; same-wave write->read (lgkm-ordered).
__global__ __launch_bounds__(1024) void attn_win(u16* __restrict__ qkv) {
    int bid = blockIdx.x;
    int tid = threadIdx.x;
    if (bid < 48) {
        int h = bid % 6, b = bid / 6;
        u16* base = qkv + (size_t)b * 1026 * 1152 + h * 64;
        int lane = tid & 63, wv = tid >> 6;  // wv 0..15
        __shared__ float sc[1026];
        __shared__ float qsh[64];
        __shared__ float redmax[16], redsum[16];
        __shared__ float pv[16][64];
        if (tid < 64) qsh[tid] = b2f(base[tid]);
        __syncthreads();
        for (int key = tid; key < 1026; key += 1024) {
            const u16* krow = base + (size_t)key * 1152 + 384;
            float acc = 0.f;
#pragma unroll
            for (int d0 = 0; d0 < 64; d0 += 8) {
                float4 qa = *(const float4*)(qsh + d0);
                float4 qb = *(const float4*)(qsh + d0 + 4);
                acc += dot8v(qa, qb, *(const uint4*)(krow + d0));
            }
            sc[key] = acc * SCALE;
        }
        __syncthreads();
        float lm = NEG_BIG;
        for (int key = tid; key < 1026; key += 1024) lm = fmaxf(lm, sc[key]);
        lm = wave_max(lm);
        if (lane == 0) redmax[wv] = lm;
        __syncthreads();
        float mx = NEG_BIG;
#pragma unroll
        for (int i = 0; i < 16; i++) mx = fmaxf(mx, redmax[i]);
        float lsum = 0.f;
        for (int key = tid; key < 1026; key += 1024) {
            float e = expf(sc[key] - mx);
            sc[key] = e;
            lsum += e;
        }
        lsum = wave_sum(lsum);
        if (lane == 0) redsum[wv] = lsum;
        __syncthreads();
        float Z = 0.f;
#pragma unroll
        for (int i = 0; i < 16; i++) Z += redsum[i];
        float acc = 0.f;
#pragma unroll
        for (int t = 0; t < 65; t++) {
            int key = wv + 16 * t;
            bool ok = key < 1026;
            int kc = ok ? key : 1025;  // row 1025 = zero pad row
            float p = ok ? sc[kc] : 0.f;
            acc += p * b2f(base[(size_t)kc * 1152 + 768 + lane]);
        }
        pv[wv][lane] = acc;
        __syncthreads();
        if (tid < 64) {
            float s = 0.f;
#pragma unroll
            for (int w2 = 0; w2 < 16; w2++) s += pv[w2][tid];
            base[tid] = f2b(s / Z);
            base[(size_t)1025 * 1152 + tid] = 0;  // att pad row (q-cols)
        }
        return;
    }
    // ---- patch branch: 16 independent waves, no barriers ----
    __shared__ float qshp[16][2][64];
    __shared__ uint2 tp[16][64];  // R32: per-lane (tok, pe-bits) broadcast
    int pbid = bid - 48;
    pbid = (pbid & 7) * 192 + (pbid >> 3);  // R27 XCD-chunk swizzle (bijective)
    int wv = tid >> 6, lane = tid & 63;
    int pair = pbid * 16 + wv;  // < 24576
    int idx = pair & 511;
    int hb = pair >> 9;
    int h = hb % 6, b = hb / 6;
    int hl = lane >> 5, l5 = lane & 31;
    int p0 = idx * 2;
    int p = p0 | hl;  // p0 even
    int r = p >> 5, c = p & 31;
    int rlo, rhi, clo, chi;
    if (r & 1) { rlo = (r - 2 < 0) ? 0 : r - 2; rhi = (r + 2 > 31) ? 31 : r + 2; }
    else       { rlo = (r - 1 < 0) ? 0 : r - 1; rhi = (r + 1 > 31) ? 31 : r + 1; }
    if (c & 1) { clo = (c - 2 < 0) ? 0 : c - 2; chi = (c + 2 > 31) ? 31 : c + 2; }
    else       { clo = (c - 1 < 0) ? 0 : c - 1; chi = (c + 1 > 31) ? 31 : c + 1; }
    int nr = rhi - rlo + 1, nc = chi - clo + 1;
    int nk = nr * nc + 1;  // + CLS at slot 0 (per half); nk in [5,26]
    int tok = 0;           // slot 0 = CLS (token 0); also lanes >= nk
    if (l5 >= 1 && l5 < nk) {
        int jj = l5 - 1;
        tok = 1 + ((rlo + jj / nc) << 5) + (clo + jj % nc);
    }
    u16* base = qkv + (size_t)b * 1026 * 1152 + h * 64;
    qshp[wv][0][lane] = b2f(base[(size_t)(1 + p0) * 1152 + lane]);
    qshp[wv][1][lane] = b2f(base[(size_t)(2 + p0) * 1152 + lane]);
    // no barrier: same-wave LDS write->read, DS pipeline orders it.
    float pe = 0.f;
    if (l5 < nk) {
        const u16* krow = base + (size_t)tok * 1152 + 384;
        const float* qv = qshp[wv][hl];
        float acc = 0.f;
#pragma unroll
        for (int d0 = 0; d0 < 64; d0 += 8) {
            float4 qa = *(const float4*)(qv + d0);
            float4 qb = *(const float4*)(qv + d0 + 4);
            acc += dot8v(qa, qb, *(const uint4*)(krow + d0));
        }
        // R30/R31: fixed shift mx=0 (exact), exp2 fold (v_exp_f32 is 2^x).
        pe = exp2f(acc * SCALE2);
    }
    float Z = half_sum(pe) + 1.f;  // pad key contributes exp(0)=1
    tp[wv][lane] = make_uint2((u32)tok, __float_as_uint(pe));  // R32 broadcast
    // PV: each half handles its own query; lane covers dims 2*l5, 2*l5+1.
    // R32: per trip j read (tok,pe) of lane (hl<<5)|j via uniform-addr b64.
    float o0 = 0.f, o1 = 0.f;
#pragma unroll
    for (int j = 0; j < 26; j++) {
        uint2 v = tp[wv][(hl << 5) | j];
        int t = (int)v.x;
        float wj = __uint_as_float(v.y);
        u32 vv = *(const u32*)(base + (size_t)t * 1152 + 768 + 2 * l5);
        o0 += wj * b2f((u16)vv);
        o1 += wj * b2f((u16)(vv >> 16));
    }
    float zi = 1.f / Z;
    u32 packed = (u32)f2b(o0 * zi) | ((u32)f2b(o1 * zi) << 16);
    *(u32*)(base + (size_t)(1 + p) * 1152 + 2 * l5) = packed;
}

extern "C" void kernel_launch(void* const* d_in, const int* in_sizes, int n_in,
                              void* d_out, int out_size, void* d_ws,
                              size_t ws_size, hipStream_t stream) {
    const float* x      = (const float*)d_in[0];
    const float* n1w    = (const float*)d_in[1];
    const float* n1b    = (const float*)d_in[2];
    const float* qkv_w  = (const float*)d_in[3];
    const float* proj_w = (const float*)d_in[4];
    const float* proj_b = (const float*)d_in[5];
    const float* n2w    = (const float*)d_in[6];
    const float* n2b    = (const float*)d_in[7];
    const float* pool_w = (const float*)d_in[8];
    const float* pool_b = (const float*)d_in[9];
    const float* n3w    = (const float*)d_in[10];
    const float* n3b    = (const float*)d_in[11];
    const float* fc1_w  = (const float*)d_in[12];
    const float* fc1_b  = (const float*)d_in[13];
    const float* fc2_w  = (const float*)d_in[14];
    const float* fc2_b  = (const float*)d_in[15];

    u16* ws = (u16*)d_ws;
    u16* h1    = ws;                      // 8208*384
    u16* qkvb  = ws + 3151872;            // 8208*1152
    u16* wb    = ws + 12607488;           // 3,096,576 bf16 weights
    float* tokf = (float*)qkvb;           // 2048*384 fp32 (reuse after proj)
    u16* h3    = qkvb + 1572864;          // 2056*384
    u16* mlp1  = qkvb + 2362368;          // 2056*1536

    // 0. prologue: LN1 || weight cvt || zero d_out (split-K accumulator)
    prologue<<<PRO_LN + PRO_CVT + PRO_ZERO, 256, 0, stream>>>(
        x, n1w, n1b, h1, qkv_w, proj_w, pool_w, fc1_w, fc2_w, wb,
        (float*)d_out);
    // 1. qkv = h1 @ qkv_w^T  (8208 x 1152 x 384), 128x128 tile
    gemm_mf<128, false, 1, false, false, false, false>
        <<<dim3(1152 / 128, 65), 256, 0, stream>>>(h1, 384, wb + W_QKV,
                                                   nullptr, nullptr, qkvb,
                                                   8208, 1152, 384);
    // 2. attention (cls leads || patch, XCD-swizzled) -> q-cols of qkvb
    attn_win<<<48 + 24576 / 16, 1024, 0, stream>>>(qkvb);
    // 3. h1 = h1 + att @ proj_w^T + proj_b  (A = qkvb q-cols, lda=1152)
    gemm_mf<64, false, 1, true, false, true, false>
        <<<dim3(384 / 64, 65), 256, 0, stream>>>(qkvb, 1152, wb + W_PROJ,
                                                 proj_b, h1, h1, 8208, 384,
                                                 384);
    // 4. midk: LN2 in-place || zero tokf (aliases qkvb — dead after proj)
    midk<<<MID_LN + MID_ZERO, 256, 0, stream>>>(h1, n2w, n2b, tokf);
    // 5. tokf += gather(h1) @ pool_w^T (+ pool_b on kp==0)  split-K=4
    gemm_mf<64, true, 4, true, false, false, true>
        <<<dim3(384 / 64, 16, 4), 256, 0, stream>>>(h1, 384, wb + W_POOL,
                                                    pool_b, nullptr, tokf,
                                                    2048, 384, 3456);
    // 6. h3 = LN3(concat(h1[:,0], tokf))  (514 blocks x 4 waves)
    ln3_concat<<<8 * 257 / 4, 256, 0, stream>>>(h1, tokf, n3w, n3b, h3);
    // 7. mlp1 = gelu(h3 @ fc1_w^T + fc1_b)  (2056 x 1536 x 384)
    gemm_mf<64, false, 1, true, true, false, false>
        <<<dim3(1536 / 64, 17), 256, 0, stream>>>(h3, 384, wb + W_FC1, fc1_b,
                                                  nullptr, mlp1, 2056, 1536,
                                                  384);
    // 8. d_out += mlp1 @ fc2_w^T (+ fc2_b on kp==0)  split-K=4, fp32 out
    gemm_mf<64, false, 4, true, false, false, true>
        <<<dim3(384 / 64, 17, 4), 256, 0, stream>>>(mlp1, 1536, wb + W_FC2,
                                                    fc2_b, nullptr, d_out,
                                                    2056, 384, 1536);
}